// Round 8
// baseline (142.867 us; speedup 1.0000x reference)
//
#include <hip/hip_runtime.h>
#include <math.h>

#define BB 64
#define SS 2048
#define FF 1024
#define HH 1024
#define NCHUNK 32

// ---- workspace layout (float offsets) ----
#define WS_PL    0                        // 2048
#define WS_XT    2048                     // 65536 : xT[f][b]
#define WS_HT    (WS_XT+65536)            // 65536 : hT[k][b]
#define WS_X2T   (WS_HT+65536)            // 65536 : x2T[j][b]
#define WS_OUTP  (WS_X2T+65536)           // 65536 : outp[j][b]
#define WS_HNT   (WS_OUTP+65536)          // 65536 : hnT[j][b]
#define WS_PACC  (WS_HNT+65536)           // 2048*1024 = 2097152

__device__ __forceinline__ float sigm(float x){ return 1.f/(1.f + __expf(-x)); }

// ---------- B: fused mask-compact + scores + softmax accumulation ----------
// Each wave owns a 16-row window; ballot-compacts it in-register; loops only unmasked rows.
__global__ __launch_bounds__(256) void kB(const float* __restrict__ enc,
                                          const int*   __restrict__ mask,
                                          const float* __restrict__ attn_W,
                                          const float* __restrict__ input,
                                          const float* __restrict__ hidden,
                                          const float* __restrict__ attn_b,
                                          float* __restrict__ scores_out,
                                          float* __restrict__ pacc,
                                          float* __restrict__ pl)
{
    const int tid  = threadIdx.x;
    const int lane = tid & 63;
    const int w    = tid >> 6;
    const int b    = blockIdx.x >> 5;
    const int c    = blockIdx.x & 31;
    const int s0   = c*64 + w*16;

    const float4* we4 = (const float4*)attn_W;
    const float4 we0 = we4[lane], we1 = we4[64+lane], we2 = we4[128+lane], we3 = we4[192+lane];

    // per-wave redundant base[b] = h.w_h + input*w_i + attn_b
    const float4* h4  = (const float4*)(hidden + (size_t)b*HH);
    const float4* wh4 = (const float4*)(attn_W + FF);
    float4 hv0 = h4[lane], hv1 = h4[64+lane], hv2 = h4[128+lane], hv3 = h4[192+lane];
    float4 wv0 = wh4[lane], wv1 = wh4[64+lane], wv2 = wh4[128+lane], wv3 = wh4[192+lane];
    float bp = hv0.x*wv0.x + hv0.y*wv0.y + hv0.z*wv0.z + hv0.w*wv0.w
             + hv1.x*wv1.x + hv1.y*wv1.y + hv1.z*wv1.z + hv1.w*wv1.w
             + hv2.x*wv2.x + hv2.y*wv2.y + hv2.z*wv2.z + hv2.w*wv2.w
             + hv3.x*wv3.x + hv3.y*wv3.y + hv3.z*wv3.z + hv3.w*wv3.w;
    #pragma unroll
    for (int off=32; off; off>>=1) bp += __shfl_xor(bp, off);
    const float bb = bp + input[b]*attn_W[FF+HH] + attn_b[0];

    // wave-local compaction of this 16-row window
    int m = 0;
    if (lane < 16) m = mask[b*SS + s0 + lane];
    unsigned long long v = __ballot(m != 0) & 0xFFFFull;
    int cw = (int)__popcll(v);

    const float4* encw = (const float4*)(enc + (size_t)(b*SS + s0)*FF);

    float l = 0.f;
    float4 a0 = make_float4(0,0,0,0), a1 = a0, a2 = a0, a3 = a0;
    float sc_keep = -1e10f;

    int npair = cw >> 1;
    for (int p=0; p<npair; ++p){
        int rA = (int)__builtin_ctzll(v); v &= v-1;
        int rB = (int)__builtin_ctzll(v); v &= v-1;
        const float4* pA = encw + (size_t)rA*(FF/4);
        const float4* pB = encw + (size_t)rB*(FF/4);
        float4 e0 = pA[lane], e1 = pA[64+lane], e2 = pA[128+lane], e3 = pA[192+lane];
        float4 f0 = pB[lane], f1 = pB[64+lane], f2 = pB[128+lane], f3 = pB[192+lane];
        float da = (e0.x*we0.x + e0.y*we0.y + e0.z*we0.z + e0.w*we0.w)
                 + (e1.x*we1.x + e1.y*we1.y + e1.z*we1.z + e1.w*we1.w)
                 + (e2.x*we2.x + e2.y*we2.y + e2.z*we2.z + e2.w*we2.w)
                 + (e3.x*we3.x + e3.y*we3.y + e3.z*we3.z + e3.w*we3.w);
        float db = (f0.x*we0.x + f0.y*we0.y + f0.z*we0.z + f0.w*we0.w)
                 + (f1.x*we1.x + f1.y*we1.y + f1.z*we1.z + f1.w*we1.w)
                 + (f2.x*we2.x + f2.y*we2.y + f2.z*we2.z + f2.w*we2.w)
                 + (f3.x*we3.x + f3.y*we3.y + f3.z*we3.z + f3.w*we3.w);
        #pragma unroll
        for (int off=32; off; off>>=1){ da += __shfl_xor(da, off); db += __shfl_xor(db, off); }
        float scA = da + bb, scB = db + bb;
        float pAe = __expf(scA), pBe = __expf(scB);
        l += pAe + pBe;
        a0.x += pAe*e0.x + pBe*f0.x; a0.y += pAe*e0.y + pBe*f0.y; a0.z += pAe*e0.z + pBe*f0.z; a0.w += pAe*e0.w + pBe*f0.w;
        a1.x += pAe*e1.x + pBe*f1.x; a1.y += pAe*e1.y + pBe*f1.y; a1.z += pAe*e1.z + pBe*f1.z; a1.w += pAe*e1.w + pBe*f1.w;
        a2.x += pAe*e2.x + pBe*f2.x; a2.y += pAe*e2.y + pBe*f2.y; a2.z += pAe*e2.z + pBe*f2.z; a2.w += pAe*e2.w + pBe*f2.w;
        a3.x += pAe*e3.x + pBe*f3.x; a3.y += pAe*e3.y + pBe*f3.y; a3.z += pAe*e3.z + pBe*f3.z; a3.w += pAe*e3.w + pBe*f3.w;
        sc_keep = (lane == rA) ? scA : sc_keep;
        sc_keep = (lane == rB) ? scB : sc_keep;
    }
    if (cw & 1){
        int rA = (int)__builtin_ctzll(v);
        const float4* pA = encw + (size_t)rA*(FF/4);
        float4 e0 = pA[lane], e1 = pA[64+lane], e2 = pA[128+lane], e3 = pA[192+lane];
        float da = (e0.x*we0.x + e0.y*we0.y + e0.z*we0.z + e0.w*we0.w)
                 + (e1.x*we1.x + e1.y*we1.y + e1.z*we1.z + e1.w*we1.w)
                 + (e2.x*we2.x + e2.y*we2.y + e2.z*we2.z + e2.w*we2.w)
                 + (e3.x*we3.x + e3.y*we3.y + e3.z*we3.z + e3.w*we3.w);
        #pragma unroll
        for (int off=32; off; off>>=1) da += __shfl_xor(da, off);
        float scA = da + bb;
        float pAe = __expf(scA);
        l += pAe;
        a0.x += pAe*e0.x; a0.y += pAe*e0.y; a0.z += pAe*e0.z; a0.w += pAe*e0.w;
        a1.x += pAe*e1.x; a1.y += pAe*e1.y; a1.z += pAe*e1.z; a1.w += pAe*e1.w;
        a2.x += pAe*e2.x; a2.y += pAe*e2.y; a2.z += pAe*e2.z; a2.w += pAe*e2.w;
        a3.x += pAe*e3.x; a3.y += pAe*e3.y; a3.z += pAe*e3.z; a3.w += pAe*e3.w;
        sc_keep = (lane == rA) ? scA : sc_keep;
    }
    if (lane < 16) scores_out[b*SS + s0 + lane] = sc_keep;   // masked rows -> -1e10

    __shared__ float4 sacc[4][256];
    __shared__ float sl[4];
    if (lane==0) sl[w] = l;
    sacc[w][lane]     = a0;
    sacc[w][64+lane]  = a1;
    sacc[w][128+lane] = a2;
    sacc[w][192+lane] = a3;
    __syncthreads();
    float4 tot = sacc[0][tid];
    #pragma unroll
    for (int q=1;q<4;q++){ float4 u = sacc[q][tid]; tot.x+=u.x; tot.y+=u.y; tot.z+=u.z; tot.w+=u.w; }
    ((float4*)(pacc + (size_t)blockIdx.x*FF))[tid] = tot;
    if (tid==0) pl[blockIdx.x] = sl[0]+sl[1]+sl[2]+sl[3];
}

// ---------- C: merge partials -> xT; q0: scores->weights; q1: hT transpose ----------
__global__ __launch_bounds__(256) void kC(const float* __restrict__ pacc,
                                          const float* __restrict__ pl,
                                          const float* __restrict__ hidden,
                                          float* __restrict__ xT,
                                          float* __restrict__ wout,
                                          float* __restrict__ hT)
{
    int b = blockIdx.x >> 2, q = blockIdx.x & 3, tid = threadIdx.x;
    float L = 0.f;
    #pragma unroll
    for (int c=0;c<NCHUNK;c++) L += pl[b*NCHUNK+c];
    float invL = 1.f/L;

    int f = q*256 + tid;
    float a = 0.f;
    #pragma unroll
    for (int c=0;c<NCHUNK;c++) a += pacc[((size_t)(b*NCHUNK+c))*FF + f];
    xT[(size_t)f*BB + b] = a*invL;

    if (q == 0){
        for (int t = tid; t < SS; t += 256){
            int idx2 = b*SS + t;
            wout[idx2] = __expf(wout[idx2]) * invL;
        }
    } else if (q == 1){
        for (int k = tid; k < HH; k += 256) hT[(size_t)k*BB + b] = hidden[(size_t)b*HH + k];
    }
}

// ---------- E: x2T[j][b] = relu(x·cW[j] + input[b]*cW[j][0] + cb[j]) ----------
// 4 j per block (1 per wave); weights LDS-staged per 128-k phase, read as wave-uniform broadcasts;
// activations per-lane (lane=batch) register chunks from L2.
__global__ __launch_bounds__(256) void kE(const float* __restrict__ xT,
                                          const float* __restrict__ input,
                                          const float* __restrict__ cW,
                                          const float* __restrict__ cb,
                                          float* __restrict__ x2T)
{
    __shared__ __align__(16) float Wl[4*128];   // 2 KB
    int tid = threadIdx.x, lane = tid & 63, w = tid >> 6;
    int j0 = blockIdx.x*4;
    int jw = j0 + w;
    float acc = 0.f;

    for (int kc=0; kc<8; ++kc){
        int k0 = kc*128;
        __syncthreads();
        for (int idx = tid; idx < 512; idx += 256){
            int row = idx >> 7, kk = idx & 127;
            Wl[row*128 + kk] = cW[(size_t)(j0+row)*(FF+1) + 1 + k0 + kk];
        }
        __syncthreads();
        #pragma unroll
        for (int ks=0; ks<128; ks+=32){
            float xv[32];
            #pragma unroll
            for (int i=0;i<32;++i) xv[i] = xT[(size_t)(k0+ks+i)*BB + lane];
            #pragma unroll
            for (int q=0;q<8;++q){
                float4 wv = *(const float4*)(Wl + w*128 + ks + q*4);
                acc += xv[q*4+0]*wv.x + xv[q*4+1]*wv.y + xv[q*4+2]*wv.z + xv[q*4+3]*wv.w;
            }
        }
    }
    acc += input[lane]*cW[(size_t)jw*(FF+1)] + cb[jw];
    x2T[(size_t)jw*BB + lane] = fmaxf(acc, 0.f);
}

// ---------- F: fused GRU — 4 j per block (1 per wave), 6 gate rows each, full K; no partials ----------
__global__ __launch_bounds__(256) void kF(const float* __restrict__ x2T,
                                          const float* __restrict__ hT,
                                          const float* __restrict__ W_ih,
                                          const float* __restrict__ W_hh,
                                          const float* __restrict__ b_ih,
                                          const float* __restrict__ b_hh,
                                          const float* __restrict__ out_W,
                                          float* __restrict__ hnT,
                                          float* __restrict__ outp)
{
    __shared__ __align__(16) float Wl[24*128];   // 12 KB
    int tid = threadIdx.x, lane = tid & 63, w = tid >> 6;
    int j0 = blockIdx.x*4;
    int jw = j0 + w;

    float ai0=0.f, ai1=0.f, ai2=0.f, ah0=0.f, ah1=0.f, ah2=0.f;

    for (int kc=0; kc<8; ++kc){
        int k0 = kc*128;
        __syncthreads();
        #pragma unroll
        for (int idx = tid; idx < 768; idx += 256){
            int row = idx >> 5, q = idx & 31;
            int wr = row / 6, g = row - wr*6;
            int jj = j0 + wr;
            const float* src = (g < 3) ? (W_ih + ((size_t)g*HH + jj)*HH + k0)
                                       : (W_hh + ((size_t)(g-3)*HH + jj)*HH + k0);
            *(float4*)(Wl + row*128 + q*4) = *(const float4*)(src + q*4);
        }
        __syncthreads();
        #pragma unroll
        for (int ks=0; ks<128; ks+=32){
            float xv[32], hv[32];
            #pragma unroll
            for (int i=0;i<32;++i){
                xv[i] = x2T[(size_t)(k0+ks+i)*BB + lane];
                hv[i] = hT [(size_t)(k0+ks+i)*BB + lane];
            }
            #pragma unroll
            for (int q=0;q<8;++q){
                int kk = ks + q*4;
                float4 w0 = *(const float4*)(Wl + (w*6+0)*128 + kk);
                float4 w1 = *(const float4*)(Wl + (w*6+1)*128 + kk);
                float4 w2 = *(const float4*)(Wl + (w*6+2)*128 + kk);
                float4 w3 = *(const float4*)(Wl + (w*6+3)*128 + kk);
                float4 w4 = *(const float4*)(Wl + (w*6+4)*128 + kk);
                float4 w5 = *(const float4*)(Wl + (w*6+5)*128 + kk);
                float x0 = xv[q*4+0], x1 = xv[q*4+1], x2 = xv[q*4+2], x3 = xv[q*4+3];
                float h0 = hv[q*4+0], h1 = hv[q*4+1], h2 = hv[q*4+2], h3 = hv[q*4+3];
                ai0 += x0*w0.x + x1*w0.y + x2*w0.z + x3*w0.w;
                ai1 += x0*w1.x + x1*w1.y + x2*w1.z + x3*w1.w;
                ai2 += x0*w2.x + x1*w2.y + x2*w2.z + x3*w2.w;
                ah0 += h0*w3.x + h1*w3.y + h2*w3.z + h3*w3.w;
                ah1 += h0*w4.x + h1*w4.y + h2*w4.z + h3*w4.w;
                ah2 += h0*w5.x + h1*w5.y + h2*w5.z + h3*w5.w;
            }
        }
    }

    float r = sigm(ai0 + b_ih[jw]       + ah0 + b_hh[jw]);
    float z = sigm(ai1 + b_ih[HH+jw]    + ah1 + b_hh[HH+jw]);
    float n = tanhf(ai2 + b_ih[2*HH+jw] + r*(ah2 + b_hh[2*HH+jw]));
    float hold = hT[(size_t)jw*BB + lane];
    float hn = (1.f - z)*n + z*hold;
    hnT[(size_t)jw*BB + lane]  = hn;
    outp[(size_t)jw*BB + lane] = fmaxf(hn, 0.f) * out_W[jw];
}

// ---------- G2: per-b — transpose hnT -> hnew and reduce outp -> out ----------
__global__ __launch_bounds__(256) void kG2(const float* __restrict__ hnT,
                                           const float* __restrict__ outp,
                                           const float* __restrict__ out_b,
                                           float* __restrict__ hnew,
                                           float* __restrict__ out)
{
    int b = blockIdx.x, tid = threadIdx.x;
    float s = 0.f;
    float4 hvec;
    int j0 = tid*4;
    hvec.x = hnT[(size_t)(j0+0)*BB + b];
    hvec.y = hnT[(size_t)(j0+1)*BB + b];
    hvec.z = hnT[(size_t)(j0+2)*BB + b];
    hvec.w = hnT[(size_t)(j0+3)*BB + b];
    *(float4*)&hnew[(size_t)b*HH + j0] = hvec;
    s += outp[(size_t)(j0+0)*BB + b] + outp[(size_t)(j0+1)*BB + b]
       + outp[(size_t)(j0+2)*BB + b] + outp[(size_t)(j0+3)*BB + b];

    __shared__ float red[256];
    red[tid] = s;
    __syncthreads();
    #pragma unroll
    for (int off=128; off>=1; off>>=1){
        if (tid < off) red[tid] += red[tid+off];
        __syncthreads();
    }
    if (tid == 0) out[b] = red[0] + out_b[0];
}

extern "C" void kernel_launch(void* const* d_in, const int* in_sizes, int n_in,
                              void* d_out, int out_size, void* d_ws, size_t ws_size,
                              hipStream_t stream) {
    const float* input     = (const float*)d_in[0];
    const float* hidden    = (const float*)d_in[1];
    const float* enc       = (const float*)d_in[2];
    const int*   mask      = (const int*)  d_in[3];
    const float* attn_W    = (const float*)d_in[4];
    const float* attn_b    = (const float*)d_in[5];
    const float* combine_W = (const float*)d_in[6];
    const float* combine_b = (const float*)d_in[7];
    const float* W_ih      = (const float*)d_in[8];
    const float* W_hh      = (const float*)d_in[9];
    const float* b_ih      = (const float*)d_in[10];
    const float* b_hh      = (const float*)d_in[11];
    const float* out_W     = (const float*)d_in[12];
    const float* out_b     = (const float*)d_in[13];

    float* out  = (float*)d_out;
    float* hnew = out + 64;            // (1,B,H)
    float* attw = out + 64 + BB*HH;    // (B,S,1) — raw scores between kB and kC
    float* ws   = (float*)d_ws;

    kB <<<BB*NCHUNK, 256, 0, stream>>>(enc, mask, attn_W, input, hidden, attn_b,
                                       attw, ws+WS_PACC, ws+WS_PL);
    kC <<<256, 256, 0, stream>>>(ws+WS_PACC, ws+WS_PL, hidden, ws+WS_XT, attw, ws+WS_HT);
    kE <<<256, 256, 0, stream>>>(ws+WS_XT, input, combine_W, combine_b, ws+WS_X2T);
    kF <<<256, 256, 0, stream>>>(ws+WS_X2T, ws+WS_HT, W_ih, W_hh, b_ih, b_hh, out_W,
                                 ws+WS_HNT, ws+WS_OUTP);
    kG2<<<64,  256, 0, stream>>>(ws+WS_HNT, ws+WS_OUTP, out_b, hnew, out);
}

// Round 9
// 102.380 us; speedup vs baseline: 1.3955x; 1.3955x over previous
//
#include <hip/hip_runtime.h>
#include <math.h>

#define BB 64
#define SS 2048
#define FF 1024
#define HH 1024
#define NCHUNK 32
#define KSPLIT 8
#define KCH 128       // HH/KSPLIT

// ---- workspace layout (float offsets) ----
#define WS_PL    0                        // 2048
#define WS_XT    2048                     // 65536
#define WS_HT    (WS_XT+65536)            // 65536
#define WS_X2T   (WS_HT+65536)            // 65536
#define WS_EPART (WS_X2T+65536)           // 8*1024*64   = 524288
#define WS_GPART (WS_EPART+524288)        // 8*6144*64   = 3145728
#define WS_PACC  (WS_GPART+3145728)       // 2048*1024   = 2097152

__device__ __forceinline__ float sigm(float x){ return 1.f/(1.f + __expf(-x)); }

// ---------- B: fused block-compaction + scores + softmax accumulation ----------
// Block owns a 64-row window (= wave width). One ballot compacts it; the 4 waves
// split the SAME list evenly (±1 row) -> balanced like R7, no kM dispatch.
__global__ __launch_bounds__(256) void kB(const float* __restrict__ enc,
                                          const int*   __restrict__ mask,
                                          const float* __restrict__ attn_W,
                                          const float* __restrict__ input,
                                          const float* __restrict__ hidden,
                                          const float* __restrict__ attn_b,
                                          float* __restrict__ scores_out,
                                          float* __restrict__ pacc,
                                          float* __restrict__ pl)
{
    const int tid  = threadIdx.x;
    const int lane = tid & 63;
    const int w    = tid >> 6;
    const int b    = blockIdx.x >> 5;
    const int c    = blockIdx.x & 31;
    const int s0   = c*64;

    const float4* we4 = (const float4*)attn_W;
    const float4 we0 = we4[lane], we1 = we4[64+lane], we2 = we4[128+lane], we3 = we4[192+lane];

    // per-wave redundant base[b] = h.w_h + input*w_i + attn_b
    const float4* h4  = (const float4*)(hidden + (size_t)b*HH);
    const float4* wh4 = (const float4*)(attn_W + FF);
    float4 hv0 = h4[lane], hv1 = h4[64+lane], hv2 = h4[128+lane], hv3 = h4[192+lane];
    float4 wv0 = wh4[lane], wv1 = wh4[64+lane], wv2 = wh4[128+lane], wv3 = wh4[192+lane];
    float bp = hv0.x*wv0.x + hv0.y*wv0.y + hv0.z*wv0.z + hv0.w*wv0.w
             + hv1.x*wv1.x + hv1.y*wv1.y + hv1.z*wv1.z + hv1.w*wv1.w
             + hv2.x*wv2.x + hv2.y*wv2.y + hv2.z*wv2.z + hv2.w*wv2.w
             + hv3.x*wv3.x + hv3.y*wv3.y + hv3.z*wv3.z + hv3.w*wv3.w;
    #pragma unroll
    for (int off=32; off; off>>=1) bp += __shfl_xor(bp, off);
    const float bb = bp + input[b]*attn_W[FF+HH] + attn_b[0];

    // block-level compaction: every wave ballots the same 64-row window
    int m = mask[b*SS + s0 + lane];
    unsigned long long v = __ballot(m != 0);
    int cnt = (int)__popcll(v);
    int share = (cnt + 3) >> 2;
    int start = w*share; if (start > cnt) start = cnt;
    int end = start + share; if (end > cnt) end = cnt;
    int mycount = end - start;

    unsigned long long vv = v;
    for (int i=0; i<start; ++i) vv &= vv - 1;   // wave-uniform scalar skip

    const float4* encw = (const float4*)(enc + (size_t)(b*SS + s0)*FF);

    float l = 0.f;
    float4 a0 = make_float4(0,0,0,0), a1 = a0, a2 = a0, a3 = a0;
    float sc_keep = 0.f;
    unsigned long long written = 0ull;

    int npair = mycount >> 1;
    for (int p=0; p<npair; ++p){
        int rA = (int)__builtin_ctzll(vv); vv &= vv-1;
        int rB = (int)__builtin_ctzll(vv); vv &= vv-1;
        const float4* pA = encw + (size_t)rA*(FF/4);
        const float4* pB = encw + (size_t)rB*(FF/4);
        float4 e0 = pA[lane], e1 = pA[64+lane], e2 = pA[128+lane], e3 = pA[192+lane];
        float4 f0 = pB[lane], f1 = pB[64+lane], f2 = pB[128+lane], f3 = pB[192+lane];
        float da = (e0.x*we0.x + e0.y*we0.y + e0.z*we0.z + e0.w*we0.w)
                 + (e1.x*we1.x + e1.y*we1.y + e1.z*we1.z + e1.w*we1.w)
                 + (e2.x*we2.x + e2.y*we2.y + e2.z*we2.z + e2.w*we2.w)
                 + (e3.x*we3.x + e3.y*we3.y + e3.z*we3.z + e3.w*we3.w);
        float db = (f0.x*we0.x + f0.y*we0.y + f0.z*we0.z + f0.w*we0.w)
                 + (f1.x*we1.x + f1.y*we1.y + f1.z*we1.z + f1.w*we1.w)
                 + (f2.x*we2.x + f2.y*we2.y + f2.z*we2.z + f2.w*we2.w)
                 + (f3.x*we3.x + f3.y*we3.y + f3.z*we3.z + f3.w*we3.w);
        #pragma unroll
        for (int off=32; off; off>>=1){ da += __shfl_xor(da, off); db += __shfl_xor(db, off); }
        float scA = da + bb, scB = db + bb;
        float pAe = __expf(scA), pBe = __expf(scB);
        l += pAe + pBe;
        a0.x += pAe*e0.x + pBe*f0.x; a0.y += pAe*e0.y + pBe*f0.y; a0.z += pAe*e0.z + pBe*f0.z; a0.w += pAe*e0.w + pBe*f0.w;
        a1.x += pAe*e1.x + pBe*f1.x; a1.y += pAe*e1.y + pBe*f1.y; a1.z += pAe*e1.z + pBe*f1.z; a1.w += pAe*e1.w + pBe*f1.w;
        a2.x += pAe*e2.x + pBe*f2.x; a2.y += pAe*e2.y + pBe*f2.y; a2.z += pAe*e2.z + pBe*f2.z; a2.w += pAe*e2.w + pBe*f2.w;
        a3.x += pAe*e3.x + pBe*f3.x; a3.y += pAe*e3.y + pBe*f3.y; a3.z += pAe*e3.z + pBe*f3.z; a3.w += pAe*e3.w + pBe*f3.w;
        sc_keep = (lane == rA) ? scA : sc_keep;
        sc_keep = (lane == rB) ? scB : sc_keep;
        written |= (1ull << rA) | (1ull << rB);
    }
    if (mycount & 1){
        int rA = (int)__builtin_ctzll(vv);
        const float4* pA = encw + (size_t)rA*(FF/4);
        float4 e0 = pA[lane], e1 = pA[64+lane], e2 = pA[128+lane], e3 = pA[192+lane];
        float da = (e0.x*we0.x + e0.y*we0.y + e0.z*we0.z + e0.w*we0.w)
                 + (e1.x*we1.x + e1.y*we1.y + e1.z*we1.z + e1.w*we1.w)
                 + (e2.x*we2.x + e2.y*we2.y + e2.z*we2.z + e2.w*we2.w)
                 + (e3.x*we3.x + e3.y*we3.y + e3.z*we3.z + e3.w*we3.w);
        #pragma unroll
        for (int off=32; off; off>>=1) da += __shfl_xor(da, off);
        float scA = da + bb;
        float pAe = __expf(scA);
        l += pAe;
        a0.x += pAe*e0.x; a0.y += pAe*e0.y; a0.z += pAe*e0.z; a0.w += pAe*e0.w;
        a1.x += pAe*e1.x; a1.y += pAe*e1.y; a1.z += pAe*e1.z; a1.w += pAe*e1.w;
        a2.x += pAe*e2.x; a2.y += pAe*e2.y; a2.z += pAe*e2.z; a2.w += pAe*e2.w;
        a3.x += pAe*e3.x; a3.y += pAe*e3.y; a3.z += pAe*e3.z; a3.w += pAe*e3.w;
        sc_keep = (lane == rA) ? scA : sc_keep;
        written |= (1ull << rA);
    }
    // scores: owner wave writes processed rows; wave 0 writes masked rows as -1e10
    if ((written >> lane) & 1ull) scores_out[b*SS + s0 + lane] = sc_keep;
    if (w == 0 && m == 0)         scores_out[b*SS + s0 + lane] = -1e10f;

    __shared__ float4 sacc[4][256];
    __shared__ float sl[4];
    if (lane==0) sl[w] = l;
    sacc[w][lane]     = a0;
    sacc[w][64+lane]  = a1;
    sacc[w][128+lane] = a2;
    sacc[w][192+lane] = a3;
    __syncthreads();
    float4 tot = sacc[0][tid];
    #pragma unroll
    for (int q=1;q<4;q++){ float4 u = sacc[q][tid]; tot.x+=u.x; tot.y+=u.y; tot.z+=u.z; tot.w+=u.w; }
    ((float4*)(pacc + (size_t)blockIdx.x*FF))[tid] = tot;
    if (tid==0) pl[blockIdx.x] = sl[0]+sl[1]+sl[2]+sl[3];
}

// ---------- C: merge partials -> xT; q0: scores->weights; q1: hT transpose; q2: out init ----------
__global__ __launch_bounds__(256) void kC(const float* __restrict__ pacc,
                                          const float* __restrict__ pl,
                                          const float* __restrict__ hidden,
                                          const float* __restrict__ out_b,
                                          float* __restrict__ xT,
                                          float* __restrict__ wout,
                                          float* __restrict__ hT,
                                          float* __restrict__ out)
{
    int b = blockIdx.x >> 2, q = blockIdx.x & 3, tid = threadIdx.x;
    float L = 0.f;
    #pragma unroll
    for (int c=0;c<NCHUNK;c++) L += pl[b*NCHUNK+c];
    float invL = 1.f/L;

    int f = q*256 + tid;
    float a = 0.f;
    #pragma unroll
    for (int c=0;c<NCHUNK;c++) a += pacc[((size_t)(b*NCHUNK+c))*FF + f];
    xT[(size_t)f*BB + b] = a*invL;

    if (q == 0){
        for (int t = tid; t < SS; t += 256){
            int idx2 = b*SS + t;
            wout[idx2] = __expf(wout[idx2]) * invL;
        }
    } else if (q == 1){
        for (int k = tid; k < HH; k += 256) hT[(size_t)k*BB + b] = hidden[(size_t)b*HH + k];
    } else if (q == 2){
        if (tid == 0) out[b] = out_b[0];
    }
}

// ---------- E1: combine-GEMM partials (j-tile 16, k-chunk 128), LDS-staged ----------
__global__ __launch_bounds__(256) void kE1(const float* __restrict__ xT,
                                           const float* __restrict__ cW,
                                           float* __restrict__ epart)
{
    __shared__ __align__(16) float Xl[KCH*64];   // 32 KB
    __shared__ __align__(16) float Wl[16*KCH];   // 8 KB
    int tid = threadIdx.x, lane = tid&63, w = tid>>6;
    int jb = blockIdx.x >> 3, kc = blockIdx.x & 7;
    int j0 = jb*16, k0 = kc*KCH;

    const float4* xs = (const float4*)(xT + (size_t)k0*BB);
    float4* xd = (float4*)Xl;
    #pragma unroll
    for (int r=tid; r<KCH*16; r+=256) xd[r] = xs[r];
    for (int idx=tid; idx<16*KCH; idx+=256){
        int row = idx>>7, kk = idx&127;
        Wl[idx] = cW[(size_t)(j0+row)*(FF+1) + 1 + k0 + kk];
    }
    __syncthreads();

    float acc[4] = {0.f,0.f,0.f,0.f};
    const float* wp = Wl + (w*4)*KCH;
    for (int kk=0; kk<KCH; kk+=4){
        float x0 = Xl[kk*64+lane], x1 = Xl[(kk+1)*64+lane];
        float x2 = Xl[(kk+2)*64+lane], x3 = Xl[(kk+3)*64+lane];
        #pragma unroll
        for (int jj=0;jj<4;jj++){
            float4 wv = *(const float4*)(wp + jj*KCH + kk);
            acc[jj] += x0*wv.x + x1*wv.y + x2*wv.z + x3*wv.w;
        }
    }
    #pragma unroll
    for (int jj=0;jj<4;jj++)
        epart[((size_t)kc*HH + j0 + w*4 + jj)*BB + lane] = acc[jj];
}

// ---------- E2: reduce partials + input column + bias, relu -> x2T ----------
__global__ __launch_bounds__(256) void kE2(const float* __restrict__ epart,
                                           const float* __restrict__ input,
                                           const float* __restrict__ cW,
                                           const float* __restrict__ cb,
                                           float* __restrict__ x2T)
{
    int tid = threadIdx.x, lane = tid&63, w = tid>>6;
    int j = blockIdx.x*4 + w;
    float s = 0.f;
    #pragma unroll
    for (int kc=0;kc<KSPLIT;kc++) s += epart[((size_t)kc*HH + j)*BB + lane];
    s += input[lane]*cW[(size_t)j*(FF+1)] + cb[j];
    x2T[(size_t)j*BB + lane] = fmaxf(s, 0.f);
}

// ---------- F1: GRU-GEMM partials (6144 rows, r-tile 16, k-chunk 128), LDS-staged ----------
__global__ __launch_bounds__(256) void kF1(const float* __restrict__ x2T,
                                           const float* __restrict__ hT,
                                           const float* __restrict__ W_ih,
                                           const float* __restrict__ W_hh,
                                           float* __restrict__ gpart)
{
    __shared__ __align__(16) float Xl[KCH*64];   // 32 KB
    __shared__ __align__(16) float Wl[16*KCH];   // 8 KB
    int tid = threadIdx.x, lane = tid&63, w = tid>>6;
    int rb = blockIdx.x >> 3, kc = blockIdx.x & 7;
    int r0 = rb*16, k0 = kc*KCH;
    bool ih = (r0 < 3*HH);
    const float* X  = ih ? x2T : hT;
    const float* Wb = ih ? (W_ih + (size_t)r0*HH) : (W_hh + (size_t)(r0-3*HH)*HH);

    const float4* xs = (const float4*)(X + (size_t)k0*BB);
    float4* xd = (float4*)Xl;
    #pragma unroll
    for (int r=tid; r<KCH*16; r+=256) xd[r] = xs[r];
    float4* wd = (float4*)Wl;
    #pragma unroll
    for (int idx4=tid; idx4<16*KCH/4; idx4+=256){
        int row = idx4>>5, kq = idx4&31;
        wd[idx4] = *(const float4*)(Wb + (size_t)row*HH + k0 + kq*4);
    }
    __syncthreads();

    float acc[4] = {0.f,0.f,0.f,0.f};
    const float* wp = Wl + (w*4)*KCH;
    for (int kk=0; kk<KCH; kk+=4){
        float x0 = Xl[kk*64+lane], x1 = Xl[(kk+1)*64+lane];
        float x2 = Xl[(kk+2)*64+lane], x3 = Xl[(kk+3)*64+lane];
        #pragma unroll
        for (int jj=0;jj<4;jj++){
            float4 wv = *(const float4*)(wp + jj*KCH + kk);
            acc[jj] += x0*wv.x + x1*wv.y + x2*wv.z + x3*wv.w;
        }
    }
    #pragma unroll
    for (int jj=0;jj<4;jj++)
        gpart[((size_t)kc*6*HH + r0 + w*4 + jj)*BB + lane] = acc[jj];
}

// ---------- F2: reduce partials, GRU gates, h_new, atomic out-projection ----------
__global__ __launch_bounds__(256) void kF2(const float* __restrict__ gpart,
                                           const float* __restrict__ b_ih,
                                           const float* __restrict__ b_hh,
                                           const float* __restrict__ hT,
                                           const float* __restrict__ out_W,
                                           float* __restrict__ hnew,
                                           float* __restrict__ out)
{
    int tid = threadIdx.x, lane = tid&63, w = tid>>6;
    int j = blockIdx.x*4 + w;
    float g[6];
    #pragma unroll
    for (int gi=0; gi<6; gi++){
        int row = (gi < 3) ? (gi*HH + j) : (3*HH + (gi-3)*HH + j);
        float s = 0.f;
        #pragma unroll
        for (int kc=0;kc<KSPLIT;kc++) s += gpart[((size_t)kc*6*HH + row)*BB + lane];
        g[gi] = s;
    }
    float r = sigm(g[0]+b_ih[j]        + g[3]+b_hh[j]);
    float z = sigm(g[1]+b_ih[HH+j]     + g[4]+b_hh[HH+j]);
    float n = tanhf(g[2]+b_ih[2*HH+j]  + r*(g[5]+b_hh[2*HH+j]));
    float hold = hT[(size_t)j*BB + lane];
    float hn = (1.f - z)*n + z*hold;
    hnew[(size_t)lane*HH + j] = hn;
    float pv = fmaxf(hn, 0.f) * out_W[j];
    __shared__ float red[4][64];
    red[w][lane] = pv;
    __syncthreads();
    if (w==0) atomicAdd(out + lane, red[0][lane]+red[1][lane]+red[2][lane]+red[3][lane]);
}

extern "C" void kernel_launch(void* const* d_in, const int* in_sizes, int n_in,
                              void* d_out, int out_size, void* d_ws, size_t ws_size,
                              hipStream_t stream) {
    const float* input     = (const float*)d_in[0];
    const float* hidden    = (const float*)d_in[1];
    const float* enc       = (const float*)d_in[2];
    const int*   mask      = (const int*)  d_in[3];
    const float* attn_W    = (const float*)d_in[4];
    const float* attn_b    = (const float*)d_in[5];
    const float* combine_W = (const float*)d_in[6];
    const float* combine_b = (const float*)d_in[7];
    const float* W_ih      = (const float*)d_in[8];
    const float* W_hh      = (const float*)d_in[9];
    const float* b_ih      = (const float*)d_in[10];
    const float* b_hh      = (const float*)d_in[11];
    const float* out_W     = (const float*)d_in[12];
    const float* out_b     = (const float*)d_in[13];

    float* out  = (float*)d_out;
    float* hnew = out + 64;            // (1,B,H)
    float* attw = out + 64 + BB*HH;    // (B,S,1) — raw scores between kB and kC
    float* ws   = (float*)d_ws;

    kB <<<BB*NCHUNK, 256, 0, stream>>>(enc, mask, attn_W, input, hidden, attn_b,
                                       attw, ws+WS_PACC, ws+WS_PL);
    kC <<<256,  256, 0, stream>>>(ws+WS_PACC, ws+WS_PL, hidden, out_b,
                                  ws+WS_XT, attw, ws+WS_HT, out);
    kE1<<<512,  256, 0, stream>>>(ws+WS_XT, combine_W, ws+WS_EPART);
    kE2<<<256,  256, 0, stream>>>(ws+WS_EPART, input, combine_W, combine_b, ws+WS_X2T);
    kF1<<<3072, 256, 0, stream>>>(ws+WS_X2T, ws+WS_HT, W_ih, W_hh, ws+WS_GPART);
    kF2<<<256,  256, 0, stream>>>(ws+WS_GPART, b_ih, b_hh, ws+WS_HT, out_W, hnew, out);
}